// Round 14
// baseline (4356.575 us; speedup 1.0000x reference)
//
#include <hip/hip_runtime.h>
#include <cstdint>
#include <cstddef>

static constexpr int TT = 1024;   // time steps
static constexpr int BB = 32;     // batch
static constexpr int CC = 256;    // channels (= 2H)
static constexpr int HH = 128;    // hidden per direction
static constexpr int GG = 512;    // 4H gates
static constexpr int MM = TT * BB;

typedef float f32x4v __attribute__((ext_vector_type(4)));
typedef short bf16x8 __attribute__((ext_vector_type(8)));

__device__ __forceinline__ float fsig(float x) { return 1.f / (1.f + __expf(-x)); }
__device__ __forceinline__ float ftanh(float x) {
  float e = __expf(2.f * x);
  return 1.f - 2.f / (e + 1.f);
}
__device__ __forceinline__ ushort bf16_rn(float x) {
  union { float f; uint u; } v; v.f = x;
  const uint r = v.u + 0x7fffu + ((v.u >> 16) & 1u);
  return (ushort)(r >> 16);
}
__device__ __forceinline__ float bf16_to_f(ushort h) {
  union { uint u; float f; } v; v.u = ((uint)h) << 16;
  return v.f;
}
__device__ __forceinline__ uint pack2(ushort a, ushort b) { return (uint)a | ((uint)b << 16); }

// LDS-only barrier: gx prefetch loads are thread-private and global stores are
// never re-read, so only lgkmcnt (LDS) ordering is required across the barrier.
__device__ __forceinline__ void barrier_lds_only() {
  asm volatile("s_waitcnt lgkmcnt(0)" ::: "memory");
  __builtin_amdgcn_s_barrier();
  asm volatile("" ::: "memory");
}

// ---------------- x[B][C][T] -> Xhi/Xlo[T*B][C] (bf16 hi/lo split) ----------------
__global__ __launch_bounds__(256) void k_transpose_cvt_in(const float* __restrict__ x,
                                                          ushort* __restrict__ xhi,
                                                          ushort* __restrict__ xlo) {
  __shared__ float tile[32][33];
  const int t0 = blockIdx.x * 32, c0 = blockIdx.y * 32, b = blockIdx.z;
  const int tx = threadIdx.x, ty = threadIdx.y;
#pragma unroll
  for (int i = 0; i < 4; i++) {
    const int cc = ty + i * 8;
    tile[cc][tx] = x[((size_t)b * CC + (c0 + cc)) * TT + t0 + tx];
  }
  __syncthreads();
#pragma unroll
  for (int i = 0; i < 4; i++) {
    const int tt = ty + i * 8;
    const float v = tile[tx][tt];
    const ushort hi = bf16_rn(v);
    const size_t idx = ((size_t)(t0 + tt) * BB + b) * CC + c0 + tx;
    xhi[idx] = hi;
    xlo[idx] = bf16_rn(v - bf16_to_f(hi));
  }
}

// ---------------- h2[T][B][C] -> out[B][C][T] ----------------
__global__ __launch_bounds__(256) void k_transpose_out(const float* __restrict__ h2,
                                                       float* __restrict__ out) {
  __shared__ float tile[32][33];
  const int t0 = blockIdx.x * 32, c0 = blockIdx.y * 32, b = blockIdx.z;
  const int tx = threadIdx.x, ty = threadIdx.y;
#pragma unroll
  for (int i = 0; i < 4; i++) {
    const int tt = ty + i * 8;
    tile[tt][tx] = h2[((size_t)(t0 + tt) * BB + b) * CC + c0 + tx];
  }
  __syncthreads();
#pragma unroll
  for (int i = 0; i < 4; i++) {
    const int cc = ty + i * 8;
    out[((size_t)b * CC + (c0 + cc)) * TT + t0 + tx] = tile[tx][cc];
  }
}

// ---------------- MFMA GEMM: gx[d][m][g] = A[m][:]·W[d][g][:] + bias ----------------
// Unchanged from R10 (verified: absmax 9.77e-4, ~50us each).
__global__ __launch_bounds__(256) void k_gemm_mfma(const ushort* __restrict__ Ahi,
                                                   const ushort* __restrict__ Alo,
                                                   const float* __restrict__ W,
                                                   const float* __restrict__ bih,
                                                   const float* __restrict__ bhh,
                                                   float* __restrict__ gx) {
  const int d = blockIdx.z;
  const int g0 = blockIdx.x * 64;
  const int m0 = blockIdx.y * 128;
  const float* Wd = W + (size_t)d * GG * CC;

  __shared__ ushort Ah[128][64];
  __shared__ ushort Al[128][64];
  __shared__ ushort Bh[64][64];
  __shared__ ushort Bl[64][64];

  const int tid = threadIdx.x;
  const int lane = tid & 63;
  const int wid = tid >> 6;
  const int wm = (wid >> 1) * 64;
  const int wg = (wid & 1) * 32;

  f32x4v acc[4][2] = {};

  for (int k0 = 0; k0 < CC; k0 += 64) {
    __syncthreads();
#pragma unroll
    for (int c = 0; c < 4; c++) {
      const int f8 = c * 256 + tid;
      const int r = f8 >> 3;
      const int kb = f8 & 7;
      const int sw = (kb ^ (r & 7)) << 3;
      const uint4 vh = *(const uint4*)&Ahi[(size_t)(m0 + r) * CC + k0 + kb * 8];
      const uint4 vl = *(const uint4*)&Alo[(size_t)(m0 + r) * CC + k0 + kb * 8];
      *(uint4*)&Ah[r][sw] = vh;
      *(uint4*)&Al[r][sw] = vl;
    }
#pragma unroll
    for (int c = 0; c < 4; c++) {
      const int f4 = c * 256 + tid;
      const int g = f4 >> 4;
      const int k4 = f4 & 15;
      const float4 wv = *(const float4*)&Wd[(size_t)(g0 + g) * CC + k0 + k4 * 4];
      ushort h0 = bf16_rn(wv.x), h1 = bf16_rn(wv.y), h2 = bf16_rn(wv.z), h3 = bf16_rn(wv.w);
      ushort l0 = bf16_rn(wv.x - bf16_to_f(h0)), l1 = bf16_rn(wv.y - bf16_to_f(h1));
      ushort l2 = bf16_rn(wv.z - bf16_to_f(h2)), l3 = bf16_rn(wv.w - bf16_to_f(h3));
      const int off = (((k4 >> 1) ^ (g & 7)) << 3) | ((k4 & 1) * 4);
      uint2 ph; ph.x = pack2(h0, h1); ph.y = pack2(h2, h3);
      uint2 pl; pl.x = pack2(l0, l1); pl.y = pack2(l2, l3);
      *(uint2*)&Bh[g][off] = ph;
      *(uint2*)&Bl[g][off] = pl;
    }
    __syncthreads();
#pragma unroll
    for (int h = 0; h < 2; h++) {
      const int kb = h * 4 + (lane >> 4);
      bf16x8 afh[4], afl[4], bfh[2], bfl[2];
#pragma unroll
      for (int i = 0; i < 4; i++) {
        const int row = wm + i * 16 + (lane & 15);
        const int sw = (kb ^ (row & 7)) << 3;
        afh[i] = *(const bf16x8*)&Ah[row][sw];
        afl[i] = *(const bf16x8*)&Al[row][sw];
      }
#pragma unroll
      for (int j = 0; j < 2; j++) {
        const int gr = wg + j * 16 + (lane & 15);
        const int sw = (kb ^ (gr & 7)) << 3;
        bfh[j] = *(const bf16x8*)&Bh[gr][sw];
        bfl[j] = *(const bf16x8*)&Bl[gr][sw];
      }
#pragma unroll
      for (int i = 0; i < 4; i++)
#pragma unroll
        for (int j = 0; j < 2; j++) {
          acc[i][j] = __builtin_amdgcn_mfma_f32_16x16x32_bf16(afh[i], bfh[j], acc[i][j], 0, 0, 0);
          acc[i][j] = __builtin_amdgcn_mfma_f32_16x16x32_bf16(afh[i], bfl[j], acc[i][j], 0, 0, 0);
          acc[i][j] = __builtin_amdgcn_mfma_f32_16x16x32_bf16(afl[i], bfh[j], acc[i][j], 0, 0, 0);
        }
    }
  }
  const int col = lane & 15;
  const int rbase = (lane >> 4) * 4;
#pragma unroll
  for (int j = 0; j < 2; j++) {
    const int g = g0 + wg + j * 16 + col;
    const float bias = bih[d * GG + g] + bhh[d * GG + g];
#pragma unroll
    for (int i = 0; i < 4; i++) {
      const int mrow = m0 + wm + i * 16 + rbase;
#pragma unroll
      for (int rr = 0; rr < 4; rr++)
        gx[((size_t)d * MM + mrow + rr) * GG + g] = acc[i][j][rr] + bias;
    }
  }
}

// ---------------- MFMA recurrence: 4 WGs, each = (direction d, batch-half bh) ------
// D[512x16] = W_hh[512x128] · H[128x16] per step via 16x16x32 bf16 MFMA, hi/lo
// 3-product. Fragment conventions identical to the VERIFIED k_gemm_mfma:
//   A/B: row|col = lane&15, k = (lane>>4)*8 + i (at MFMA k-offset kb*32)
//   C/D: col = lane&15 (batch), row = (lane>>4)*4 + reg (gate-row-local)
// -> i,f,g,o of each (j,b) land in ONE lane's registers: act lane-local, c in VGPRs.
// R13 bug fixed here: H-plane LDS read/write now share ONE layout:
//   plane = 2048 ushorts (128 k x 16 col), slot = kb*512 + ko*128 + col*8 + i
//   B_lds[buf][hl][plane]: hl-stride 2048, buf-stride 4096, total 8192 u16 = 16 KB.
// (R13 wrote hi at buf-stride 8192 but read it at buf-stride 4096 -> dot saw h_hi=0.)
__global__ __launch_bounds__(512, 1) void k_lstm_rec_mfma(const float* __restrict__ gx,
                                                          const float* __restrict__ Whh,
                                                          float* __restrict__ hf32,
                                                          ushort* __restrict__ hhi,
                                                          ushort* __restrict__ hlo,
                                                          int store_bf16) {
  const int bh = blockIdx.x & 1;   // batch half: cols 16bh..16bh+15
  const int d  = blockIdx.x >> 1;  // direction
  const int tid = threadIdx.x;
  const int l   = tid & 63;
  const int w   = tid >> 6;        // wave 0..7 -> gate-row tile [16w,16w+16) per gate
  const int col = l & 15;          // batch col within half
  const int oct = l >> 4;          // k-octet (A/B) / row-quad (C/D)
  const int b_global = bh * 16 + col;
  const int jbase = 16 * w + oct * 4;   // hidden j for reg r = jbase + r

  __shared__ ushort B_lds[8192];   // [buf:4096][hl:2048][slot], 16 KB

  // ---- W_hh A-fragments (bf16 hi/lo), resident for the whole kernel ----
  bf16x8 Afh[4][4], Afl[4][4];  // [gate][kb]
  {
    const float* wbase = Whh + (size_t)d * GG * HH;
#pragma unroll
    for (int g2 = 0; g2 < 4; g2++) {
#pragma unroll
      for (int kb = 0; kb < 4; kb++) {
        const float* wr = wbase + (size_t)(g2 * 128 + 16 * w + col) * HH + kb * 32 + oct * 8;
        float f[8];
        *(float4*)&f[0] = *(const float4*)&wr[0];
        *(float4*)&f[4] = *(const float4*)&wr[4];
        bf16x8 vh, vl;
#pragma unroll
        for (int i = 0; i < 8; i++) {
          const ushort hi = bf16_rn(f[i]);
          vh[i] = (short)hi;
          vl[i] = (short)bf16_rn(f[i] - bf16_to_f(hi));
        }
        Afh[g2][kb] = vh;
        Afl[g2][kb] = vl;
      }
    }
  }

  // zero both buffers (h(t=-1) = 0)
  {
    ushort4 z; z.x = z.y = z.z = z.w = 0;
    for (int i = tid; i < 8192 / 4; i += 512) ((ushort4*)B_lds)[i] = z;
  }

  float c0 = 0.f, c1 = 0.f, c2 = 0.f, c3 = 0.f;

  const float* gxd = gx + (size_t)d * TT * BB * GG;
  int t = d ? (TT - 1) : 0;
  const int tdir = d ? -1 : 1;

  // gx for current step: [gate][reg], float4 (j contiguous)
  float cur[4][4];
#pragma unroll
  for (int g2 = 0; g2 < 4; g2++) {
    const float4 v = *(const float4*)&gxd[((size_t)t * BB + b_global) * GG + g2 * 128 + jbase];
    cur[g2][0] = v.x; cur[g2][1] = v.y; cur[g2][2] = v.z; cur[g2][3] = v.w;
  }
  __syncthreads();

  // write slot for this lane's 4 h values (j = jbase..jbase+3 -> one 8B run)
  const int wslot = (jbase >> 5) * 512 + ((jbase >> 3) & 3) * 128 + col * 8 + (jbase & 7);

  int p = 0;
  for (int s = 0; s < TT; s++) {
    // prefetch next step's gx (floats across the lgkm-only barrier)
    float nxt[4][4];
    if (s + 1 < TT) {
      const int tn = t + tdir;
#pragma unroll
      for (int g2 = 0; g2 < 4; g2++) {
        const float4 v = *(const float4*)&gxd[((size_t)tn * BB + b_global) * GG + g2 * 128 + jbase];
        nxt[g2][0] = v.x; nxt[g2][1] = v.y; nxt[g2][2] = v.z; nxt[g2][3] = v.w;
      }
    } else {
#pragma unroll
      for (int g2 = 0; g2 < 4; g2++)
#pragma unroll
        for (int r = 0; r < 4; r++) nxt[g2][r] = 0.f;
    }

    // read H fragments: k = kb*32 + oct*8 + i, col; contiguous 16B/lane, conflict-free
    bf16x8 Bhf[4], Blf[4];
#pragma unroll
    for (int kb = 0; kb < 4; kb++) {
      const int base = p * 4096 + kb * 512 + oct * 128 + col * 8;
      Bhf[kb] = *(const bf16x8*)&B_lds[base];
      Blf[kb] = *(const bf16x8*)&B_lds[base + 2048];
    }

    // MFMA: acc[gate] = W·H (hi/lo 3-product)
    f32x4v acc[4] = {};
#pragma unroll
    for (int g2 = 0; g2 < 4; g2++) {
#pragma unroll
      for (int kb = 0; kb < 4; kb++) {
        acc[g2] = __builtin_amdgcn_mfma_f32_16x16x32_bf16(Afh[g2][kb], Bhf[kb], acc[g2], 0, 0, 0);
        acc[g2] = __builtin_amdgcn_mfma_f32_16x16x32_bf16(Afh[g2][kb], Blf[kb], acc[g2], 0, 0, 0);
        acc[g2] = __builtin_amdgcn_mfma_f32_16x16x32_bf16(Afl[g2][kb], Bhf[kb], acc[g2], 0, 0, 0);
      }
    }

    // act (lane-local; 4 (j,b) pairs) + h emission
    ushort hi4[4], lo4[4];
    float hv[4];
#pragma unroll
    for (int r = 0; r < 4; r++) {
      const float i_g = fsig(acc[0][r] + cur[0][r]);
      const float f_g = fsig(acc[1][r] + cur[1][r]);
      const float g_g = ftanh(acc[2][r] + cur[2][r]);
      const float o_g = fsig(acc[3][r] + cur[3][r]);
      float cc = (r == 0 ? c0 : r == 1 ? c1 : r == 2 ? c2 : c3);
      cc = f_g * cc + i_g * g_g;
      if (r == 0) c0 = cc; else if (r == 1) c1 = cc; else if (r == 2) c2 = cc; else c3 = cc;
      const float h = o_g * ftanh(cc);
      hv[r] = h;
      hi4[r] = bf16_rn(h);
      lo4[r] = bf16_rn(h - bf16_to_f(hi4[r]));
    }

    // write next-step H planes (one 8B LDS write per plane)
    {
      const int bufoff = (p ^ 1) * 4096;
      ushort4 vh; vh.x = hi4[0]; vh.y = hi4[1]; vh.z = hi4[2]; vh.w = hi4[3];
      ushort4 vl; vl.x = lo4[0]; vl.y = lo4[1]; vl.z = lo4[2]; vl.w = lo4[3];
      *(ushort4*)&B_lds[bufoff + wslot] = vh;
      *(ushort4*)&B_lds[bufoff + 2048 + wslot] = vl;
    }

    // global store (j contiguous; never re-read before kernel end)
    {
      const size_t m = (size_t)t * BB + b_global;
      if (store_bf16) {
        ushort4 vh; vh.x = hi4[0]; vh.y = hi4[1]; vh.z = hi4[2]; vh.w = hi4[3];
        ushort4 vl; vl.x = lo4[0]; vl.y = lo4[1]; vl.z = lo4[2]; vl.w = lo4[3];
        *(ushort4*)&hhi[m * CC + d * HH + jbase] = vh;
        *(ushort4*)&hlo[m * CC + d * HH + jbase] = vl;
      } else {
        float4 vf; vf.x = hv[0]; vf.y = hv[1]; vf.z = hv[2]; vf.w = hv[3];
        *(float4*)&hf32[m * CC + d * HH + jbase] = vf;
      }
    }

    barrier_lds_only();  // H(p^1) complete; next iteration reads it
    p ^= 1;
    t += tdir;
#pragma unroll
    for (int g2 = 0; g2 < 4; g2++)
#pragma unroll
      for (int r = 0; r < 4; r++) cur[g2][r] = nxt[g2][r];
  }
}

extern "C" void kernel_launch(void* const* d_in, const int* in_sizes, int n_in,
                              void* d_out, int out_size, void* d_ws, size_t ws_size,
                              hipStream_t stream) {
  const float* x    = (const float*)d_in[0];
  const float* W_ih = (const float*)d_in[1];  // [2][2][512][256]
  const float* W_hh = (const float*)d_in[2];  // [2][2][512][128]
  const float* b_ih = (const float*)d_in[3];  // [2][2][512]
  const float* b_hh = (const float*)d_in[4];
  float* out = (float*)d_out;

  if (ws_size < (size_t)160 * 1024 * 1024) return;

  // A-region (32 MiB) recycled: Xhi/Xlo -> h1hi/h1lo -> h2 fp32
  char* ws = (char*)d_ws;
  ushort* abf_hi = (ushort*)ws;                              // 16 MiB
  ushort* abf_lo = (ushort*)(ws + (size_t)16 * 1024 * 1024); // 16 MiB
  float*  h2     = (float*)ws;                               // 32 MiB (rec1 output)
  float*  gxbuf  = (float*)(ws + (size_t)32 * 1024 * 1024);  // [D][M][512] 128 MiB

  const dim3 tb(32, 8);
  const dim3 tg(TT / 32, CC / 32, BB);
  const dim3 gemm_grid(GG / 64, MM / 128, 2);

  k_transpose_cvt_in<<<tg, tb, 0, stream>>>(x, abf_hi, abf_lo);
  k_gemm_mfma<<<gemm_grid, 256, 0, stream>>>(abf_hi, abf_lo, W_ih, b_ih, b_hh, gxbuf);
  k_lstm_rec_mfma<<<4, 512, 0, stream>>>(gxbuf, W_hh, nullptr, abf_hi, abf_lo, 1);
  k_gemm_mfma<<<gemm_grid, 256, 0, stream>>>(abf_hi, abf_lo, W_ih + 2 * GG * CC,
                                             b_ih + 2 * GG, b_hh + 2 * GG, gxbuf);
  k_lstm_rec_mfma<<<4, 512, 0, stream>>>(gxbuf, W_hh + 2 * GG * HH, h2, nullptr, nullptr, 0);
  k_transpose_out<<<tg, tb, 0, stream>>>(h2, out);
}

// Round 15
// 1800.147 us; speedup vs baseline: 2.4201x; 2.4201x over previous
//
#include <hip/hip_runtime.h>
#include <cstdint>
#include <cstddef>

static constexpr int TT = 1024;   // time steps
static constexpr int BB = 32;     // batch
static constexpr int CC = 256;    // channels (= 2H)
static constexpr int HH = 128;    // hidden per direction
static constexpr int GG = 512;    // 4H gates
static constexpr int MM = TT * BB;

typedef float f32x4v __attribute__((ext_vector_type(4)));
typedef short bf16x8 __attribute__((ext_vector_type(8)));

__device__ __forceinline__ float fsig(float x) { return 1.f / (1.f + __expf(-x)); }
__device__ __forceinline__ float ftanh(float x) {
  float e = __expf(2.f * x);
  return 1.f - 2.f / (e + 1.f);
}
__device__ __forceinline__ ushort bf16_rn(float x) {
  union { float f; uint u; } v; v.f = x;
  const uint r = v.u + 0x7fffu + ((v.u >> 16) & 1u);
  return (ushort)(r >> 16);
}
__device__ __forceinline__ float bf16_to_f(ushort h) {
  union { uint u; float f; } v; v.u = ((uint)h) << 16;
  return v.f;
}
__device__ __forceinline__ uint pack2(ushort a, ushort b) { return (uint)a | ((uint)b << 16); }

// ---------------- x[B][C][T] -> Xhi/Xlo[T*B][C] (bf16 hi/lo split) ----------------
__global__ __launch_bounds__(256) void k_transpose_cvt_in(const float* __restrict__ x,
                                                          ushort* __restrict__ xhi,
                                                          ushort* __restrict__ xlo) {
  __shared__ float tile[32][33];
  const int t0 = blockIdx.x * 32, c0 = blockIdx.y * 32, b = blockIdx.z;
  const int tx = threadIdx.x, ty = threadIdx.y;
#pragma unroll
  for (int i = 0; i < 4; i++) {
    const int cc = ty + i * 8;
    tile[cc][tx] = x[((size_t)b * CC + (c0 + cc)) * TT + t0 + tx];
  }
  __syncthreads();
#pragma unroll
  for (int i = 0; i < 4; i++) {
    const int tt = ty + i * 8;
    const float v = tile[tx][tt];
    const ushort hi = bf16_rn(v);
    const size_t idx = ((size_t)(t0 + tt) * BB + b) * CC + c0 + tx;
    xhi[idx] = hi;
    xlo[idx] = bf16_rn(v - bf16_to_f(hi));
  }
}

// ---------------- h2[T][B][C] -> out[B][C][T] ----------------
__global__ __launch_bounds__(256) void k_transpose_out(const float* __restrict__ h2,
                                                       float* __restrict__ out) {
  __shared__ float tile[32][33];
  const int t0 = blockIdx.x * 32, c0 = blockIdx.y * 32, b = blockIdx.z;
  const int tx = threadIdx.x, ty = threadIdx.y;
#pragma unroll
  for (int i = 0; i < 4; i++) {
    const int tt = ty + i * 8;
    tile[tt][tx] = h2[((size_t)(t0 + tt) * BB + b) * CC + c0 + tx];
  }
  __syncthreads();
#pragma unroll
  for (int i = 0; i < 4; i++) {
    const int cc = ty + i * 8;
    out[((size_t)b * CC + (c0 + cc)) * TT + t0 + tx] = tile[tx][cc];
  }
}

// ---------------- MFMA GEMM: gx[d][m][g] = A[m][:]·W[d][g][:] + bias ----------------
// Verified R10/R14: absmax 9.77e-4, ~50us each.
__global__ __launch_bounds__(256) void k_gemm_mfma(const ushort* __restrict__ Ahi,
                                                   const ushort* __restrict__ Alo,
                                                   const float* __restrict__ W,
                                                   const float* __restrict__ bih,
                                                   const float* __restrict__ bhh,
                                                   float* __restrict__ gx) {
  const int d = blockIdx.z;
  const int g0 = blockIdx.x * 64;
  const int m0 = blockIdx.y * 128;
  const float* Wd = W + (size_t)d * GG * CC;

  __shared__ ushort Ah[128][64];
  __shared__ ushort Al[128][64];
  __shared__ ushort Bh[64][64];
  __shared__ ushort Bl[64][64];

  const int tid = threadIdx.x;
  const int lane = tid & 63;
  const int wid = tid >> 6;
  const int wm = (wid >> 1) * 64;
  const int wg = (wid & 1) * 32;

  f32x4v acc[4][2] = {};

  for (int k0 = 0; k0 < CC; k0 += 64) {
    __syncthreads();
#pragma unroll
    for (int c = 0; c < 4; c++) {
      const int f8 = c * 256 + tid;
      const int r = f8 >> 3;
      const int kb = f8 & 7;
      const int sw = (kb ^ (r & 7)) << 3;
      const uint4 vh = *(const uint4*)&Ahi[(size_t)(m0 + r) * CC + k0 + kb * 8];
      const uint4 vl = *(const uint4*)&Alo[(size_t)(m0 + r) * CC + k0 + kb * 8];
      *(uint4*)&Ah[r][sw] = vh;
      *(uint4*)&Al[r][sw] = vl;
    }
#pragma unroll
    for (int c = 0; c < 4; c++) {
      const int f4 = c * 256 + tid;
      const int g = f4 >> 4;
      const int k4 = f4 & 15;
      const float4 wv = *(const float4*)&Wd[(size_t)(g0 + g) * CC + k0 + k4 * 4];
      ushort h0 = bf16_rn(wv.x), h1 = bf16_rn(wv.y), h2 = bf16_rn(wv.z), h3 = bf16_rn(wv.w);
      ushort l0 = bf16_rn(wv.x - bf16_to_f(h0)), l1 = bf16_rn(wv.y - bf16_to_f(h1));
      ushort l2 = bf16_rn(wv.z - bf16_to_f(h2)), l3 = bf16_rn(wv.w - bf16_to_f(h3));
      const int off = (((k4 >> 1) ^ (g & 7)) << 3) | ((k4 & 1) * 4);
      uint2 ph; ph.x = pack2(h0, h1); ph.y = pack2(h2, h3);
      uint2 pl; pl.x = pack2(l0, l1); pl.y = pack2(l2, l3);
      *(uint2*)&Bh[g][off] = ph;
      *(uint2*)&Bl[g][off] = pl;
    }
    __syncthreads();
#pragma unroll
    for (int h = 0; h < 2; h++) {
      const int kb = h * 4 + (lane >> 4);
      bf16x8 afh[4], afl[4], bfh[2], bfl[2];
#pragma unroll
      for (int i = 0; i < 4; i++) {
        const int row = wm + i * 16 + (lane & 15);
        const int sw = (kb ^ (row & 7)) << 3;
        afh[i] = *(const bf16x8*)&Ah[row][sw];
        afl[i] = *(const bf16x8*)&Al[row][sw];
      }
#pragma unroll
      for (int j = 0; j < 2; j++) {
        const int gr = wg + j * 16 + (lane & 15);
        const int sw = (kb ^ (gr & 7)) << 3;
        bfh[j] = *(const bf16x8*)&Bh[gr][sw];
        bfl[j] = *(const bf16x8*)&Bl[gr][sw];
      }
#pragma unroll
      for (int i = 0; i < 4; i++)
#pragma unroll
        for (int j = 0; j < 2; j++) {
          acc[i][j] = __builtin_amdgcn_mfma_f32_16x16x32_bf16(afh[i], bfh[j], acc[i][j], 0, 0, 0);
          acc[i][j] = __builtin_amdgcn_mfma_f32_16x16x32_bf16(afh[i], bfl[j], acc[i][j], 0, 0, 0);
          acc[i][j] = __builtin_amdgcn_mfma_f32_16x16x32_bf16(afl[i], bfh[j], acc[i][j], 0, 0, 0);
        }
    }
  }
  const int col = lane & 15;
  const int rbase = (lane >> 4) * 4;
#pragma unroll
  for (int j = 0; j < 2; j++) {
    const int g = g0 + wg + j * 16 + col;
    const float bias = bih[d * GG + g] + bhh[d * GG + g];
#pragma unroll
    for (int i = 0; i < 4; i++) {
      const int mrow = m0 + wm + i * 16 + rbase;
#pragma unroll
      for (int rr = 0; rr < 4; rr++)
        gx[((size_t)d * MM + mrow + rr) * GG + g] = acc[i][j][rr] + bias;
    }
  }
}

// ---------------- persistent recurrence: one WG per (d,b) — R5 structure EXACT ------
// Best measured rec across 10 structural variants (R5: 798us). Thread (q=tid>>7,
// j=tid&127): 4 gates x 32-K quarter, float4 weights register-resident (AGPR ok;
// plain-C fma reads them at full rate). 8 uniform b128 h-reads/thread, part[] LDS
// reduction, 2-wave act, plain __syncthreads (R8 showed lgkm-only barrier is NOT
// faster here). Only change vs R5: optional bf16 hi/lo h output for the MFMA GEMM.
// MFMA-formulated rec (R14: 2099us @ 4 CUs) and all other variants measured worse.
__global__ __launch_bounds__(512, 1) void k_lstm_rec(const float* __restrict__ gx,
                                                     const float* __restrict__ Whh,
                                                     float* __restrict__ hf32,
                                                     ushort* __restrict__ hhi,
                                                     ushort* __restrict__ hlo,
                                                     int store_bf16) {
  const int b = blockIdx.x & 31;
  const int d = blockIdx.x >> 5;
  const int tid = threadIdx.x;
  const int q = tid >> 7;       // K-quarter (wave-uniform)
  const int j = tid & 127;
  __shared__ __align__(16) float h_s[HH];
  __shared__ __align__(16) float part[4][HH][4];

  float4 w4[4][8];
  {
    const float* base = Whh + (size_t)d * GG * HH;
#pragma unroll
    for (int gi = 0; gi < 4; gi++) {
      const float4* wrow = (const float4*)(base + (size_t)(gi * HH + j) * HH + q * 32);
#pragma unroll
      for (int k = 0; k < 8; k++) w4[gi][k] = wrow[k];
    }
  }
#pragma unroll
  for (int gi = 0; gi < 4; gi++)
#pragma unroll
    for (int k = 0; k < 8; k++)
      asm volatile("" : "+v"(w4[gi][k].x), "+v"(w4[gi][k].y), "+v"(w4[gi][k].z), "+v"(w4[gi][k].w));

  if (tid < HH) h_s[tid] = 0.f;
  float c = 0.f;

  const float* gxb = gx + ((size_t)d * TT * BB + b) * (size_t)GG;
  const size_t stride = (size_t)BB * GG;
  int t = d ? (TT - 1) : 0;
  const int tdir = d ? -1 : 1;
  const bool is_act = (tid < HH);

  float gxc0 = 0.f, gxc1 = 0.f, gxc2 = 0.f, gxc3 = 0.f;
  if (is_act) {
    const float* g0 = gxb + (size_t)t * stride + j;
    gxc0 = g0[0]; gxc1 = g0[HH]; gxc2 = g0[2 * HH]; gxc3 = g0[3 * HH];
  }
  __syncthreads();

  for (int s = 0; s < TT; s++) {
    // prefetch next step's gx (independent of h)
    float gxn0 = 0.f, gxn1 = 0.f, gxn2 = 0.f, gxn3 = 0.f;
    if (is_act && s + 1 < TT) {
      const float* g0 = gxb + (size_t)(t + tdir) * stride + j;
      gxn0 = g0[0]; gxn1 = g0[HH]; gxn2 = g0[2 * HH]; gxn3 = g0[3 * HH];
    }

    // h K-slice: 8 uniform b128 reads
    const float4* hq = (const float4*)(h_s + q * 32);
    float a0 = 0.f, a1 = 0.f, a2 = 0.f, a3 = 0.f;
#pragma unroll
    for (int k = 0; k < 8; k++) {
      const float4 hv = hq[k];
      a0 = fmaf(w4[0][k].x, hv.x, a0); a0 = fmaf(w4[0][k].y, hv.y, a0);
      a0 = fmaf(w4[0][k].z, hv.z, a0); a0 = fmaf(w4[0][k].w, hv.w, a0);
      a1 = fmaf(w4[1][k].x, hv.x, a1); a1 = fmaf(w4[1][k].y, hv.y, a1);
      a1 = fmaf(w4[1][k].z, hv.z, a1); a1 = fmaf(w4[1][k].w, hv.w, a1);
      a2 = fmaf(w4[2][k].x, hv.x, a2); a2 = fmaf(w4[2][k].y, hv.y, a2);
      a2 = fmaf(w4[2][k].z, hv.z, a2); a2 = fmaf(w4[2][k].w, hv.w, a2);
      a3 = fmaf(w4[3][k].x, hv.x, a3); a3 = fmaf(w4[3][k].y, hv.y, a3);
      a3 = fmaf(w4[3][k].z, hv.z, a3); a3 = fmaf(w4[3][k].w, hv.w, a3);
    }
    *(float4*)&part[q][j][0] = make_float4(a0, a1, a2, a3);
    __syncthreads();

    if (is_act) {
      const float4 p0 = *(const float4*)&part[0][j][0];
      const float4 p1 = *(const float4*)&part[1][j][0];
      const float4 p2 = *(const float4*)&part[2][j][0];
      const float4 p3 = *(const float4*)&part[3][j][0];
      const float i_g = fsig(p0.x + p1.x + p2.x + p3.x + gxc0);
      const float f_g = fsig(p0.y + p1.y + p2.y + p3.y + gxc1);
      const float g_g = ftanh(p0.z + p1.z + p2.z + p3.z + gxc2);
      const float o_g = fsig(p0.w + p1.w + p2.w + p3.w + gxc3);
      c = f_g * c + i_g * g_g;
      const float h = o_g * ftanh(c);
      h_s[j] = h;
      const size_t idx = ((size_t)t * BB + b) * CC + d * HH + j;
      if (store_bf16) {
        const ushort hi = bf16_rn(h);
        hhi[idx] = hi;
        hlo[idx] = bf16_rn(h - bf16_to_f(hi));
      } else {
        hf32[idx] = h;
      }
    }
    __syncthreads();
    gxc0 = gxn0; gxc1 = gxn1; gxc2 = gxn2; gxc3 = gxn3;
    t += tdir;
  }
}

extern "C" void kernel_launch(void* const* d_in, const int* in_sizes, int n_in,
                              void* d_out, int out_size, void* d_ws, size_t ws_size,
                              hipStream_t stream) {
  const float* x    = (const float*)d_in[0];
  const float* W_ih = (const float*)d_in[1];  // [2][2][512][256]
  const float* W_hh = (const float*)d_in[2];  // [2][2][512][128]
  const float* b_ih = (const float*)d_in[3];  // [2][2][512]
  const float* b_hh = (const float*)d_in[4];
  float* out = (float*)d_out;

  if (ws_size < (size_t)160 * 1024 * 1024) return;

  // A-region (32 MiB) recycled: Xhi/Xlo -> h1hi/h1lo -> h2 fp32
  char* ws = (char*)d_ws;
  ushort* abf_hi = (ushort*)ws;                              // 16 MiB
  ushort* abf_lo = (ushort*)(ws + (size_t)16 * 1024 * 1024); // 16 MiB
  float*  h2     = (float*)ws;                               // 32 MiB (rec1 output)
  float*  gxbuf  = (float*)(ws + (size_t)32 * 1024 * 1024);  // [D][M][512] 128 MiB

  const dim3 tb(32, 8);
  const dim3 tg(TT / 32, CC / 32, BB);
  const dim3 gemm_grid(GG / 64, MM / 128, 2);

  k_transpose_cvt_in<<<tg, tb, 0, stream>>>(x, abf_hi, abf_lo);
  k_gemm_mfma<<<gemm_grid, 256, 0, stream>>>(abf_hi, abf_lo, W_ih, b_ih, b_hh, gxbuf);
  k_lstm_rec<<<64, 512, 0, stream>>>(gxbuf, W_hh, nullptr, abf_hi, abf_lo, 1);
  k_gemm_mfma<<<gemm_grid, 256, 0, stream>>>(abf_hi, abf_lo, W_ih + 2 * GG * CC,
                                             b_ih + 2 * GG, b_hh + 2 * GG, gxbuf);
  k_lstm_rec<<<64, 512, 0, stream>>>(gxbuf, W_hh + 2 * GG * HH, h2, nullptr, nullptr, 0);
  k_transpose_out<<<tg, tb, 0, stream>>>(h2, out);
}